// Round 3
// baseline (228.132 us; speedup 1.0000x reference)
//
#include <hip/hip_runtime.h>
#include <hip/hip_bf16.h>

// Problem constants (from reference)
#define GG   8
#define NN   10000
#define EE   160000       // = 625 * 256 exactly
#define DIN  300
#define KP1  320          // DIN padded to mult of 32
#define DH   256
#define DOUT 128
#define LN_EPS 1e-5f

typedef short bf16x8 __attribute__((ext_vector_type(8)));
typedef float f32x4  __attribute__((ext_vector_type(4)));
typedef ushort u16x8 __attribute__((ext_vector_type(8)));

__device__ inline float bf2f(ushort u) {
    union { unsigned int i; float f; } x;
    x.i = ((unsigned int)u) << 16;
    return x.f;
}
__device__ inline ushort f2b(float f) {
    union { float f; unsigned int u; } x;
    x.f = f;
    unsigned int u = x.u;
    return (ushort)((u + 0x7fffu + ((u >> 16) & 1u)) >> 16);  // RNE (finite values)
}
__device__ inline short bcvt(float f) {
    __hip_bfloat16 h = __float2bfloat16(f);   // RNE; compiler emits v_cvt
    return *reinterpret_cast<short*>(&h);
}

// ---------------------------------------------------------------------------
// k_util: zero cnt + cast W1 -> w1t [256][320] + cast W2 -> w2t [128][256]
// ---------------------------------------------------------------------------
__global__ __launch_bounds__(256) void k_util(const float* __restrict__ W1,
                                              const float* __restrict__ W2,
                                              ushort* __restrict__ w1t,
                                              ushort* __restrict__ w2t,
                                              int* __restrict__ cnt) {
    int i = blockIdx.x * blockDim.x + threadIdx.x;
    if (i < GG * NN) cnt[i] = 0;
    if (i < DH * KP1) {
        int n = i / KP1, k = i % KP1;
        w1t[i] = (k < DIN) ? f2b(W1[(size_t)k * DH + n]) : 0;
    }
    if (i < DOUT * DH) {
        int n = i / DH, k = i % DH;
        w2t[i] = f2b(W2[(size_t)k * DOUT + n]);
    }
}

// ---------------------------------------------------------------------------
// CSR build kernels
// ---------------------------------------------------------------------------
__global__ __launch_bounds__(256) void k_count(const int* __restrict__ ei,
                                               int* __restrict__ cnt,
                                               int* __restrict__ slot) {
    int bid = blockIdx.x;
    int g = bid & 7;
    int e = (bid >> 3) * 256 + threadIdx.x;       // e < EE exactly
    int dst = ei[(size_t)g * 2 * EE + EE + e];
    slot[(size_t)g * EE + e] = atomicAdd(&cnt[g * NN + dst], 1);
}

__global__ void k_scan(const int* __restrict__ cnt, int* __restrict__ rowptr,
                       float* __restrict__ dinv) {
    int g = blockIdx.x;
    int t = threadIdx.x;                // 256 threads
    const int per = (NN + 255) / 256;   // 40
    __shared__ int sums[256];
    __shared__ int offs[257];
    int base = t * per;
    int s = 0;
    for (int i = 0; i < per; i++) {
        int n = base + i;
        if (n < NN) s += cnt[g * NN + n];
    }
    sums[t] = s;
    __syncthreads();
    if (t == 0) {
        int acc = 0;
        for (int i = 0; i < 256; i++) { offs[i] = acc; acc += sums[i]; }
        offs[256] = acc;
    }
    __syncthreads();
    int run = offs[t];
    for (int i = 0; i < per; i++) {
        int n = base + i;
        if (n < NN) {
            int c = cnt[g * NN + n];
            rowptr[g * (NN + 1) + n] = run;
            dinv[g * NN + n] = 1.0f / sqrtf(1.0f + (float)c);
            run += c;
        }
    }
    if (t == 255) rowptr[g * (NN + 1) + NN] = offs[256];
}

__global__ __launch_bounds__(256) void k_fill(const int* __restrict__ ei,
                                              const int* __restrict__ rowptr,
                                              const int* __restrict__ slot,
                                              const float* __restrict__ dinv,
                                              int2* __restrict__ edges) {
    int bid = blockIdx.x;
    int g = bid & 7;
    int e = (bid >> 3) * 256 + threadIdx.x;
    int src = ei[(size_t)g * 2 * EE + e];
    int dst = ei[(size_t)g * 2 * EE + EE + e];
    int pos = rowptr[g * (NN + 1) + dst] + slot[(size_t)g * EE + e];
    float coef = dinv[g * NN + src] * dinv[g * NN + dst];
    int2 rec;
    rec.x = src;
    rec.y = __float_as_int(coef);
    edges[(size_t)g * EE + pos] = rec;
}

// ---------------------------------------------------------------------------
// GEMM1 with fused fp32->bf16 cast of A:  C[80000,256] = bf16(x[80000,300]) @ W1
// 128x256 tile, 512 threads (8 waves, 2x4), BK=32.
// SYNC STRUCTURE = verified round-0 baseline (two __syncthreads per K-step,
// reg-staged A + ds_write, next-iter A prefetch before barrier).
// NEW (validated by R2 cold-pass): Bs XOR(row&3) swizzle — source column
// pre-swizzled (gload_lds dest must stay linear, m104/m173), fragment read
// applies the same XOR.  8-way ds_read_b128 conflict -> 4-way.
// As keeps padded stride 36 floats (2-way, free per m136).
// ---------------------------------------------------------------------------
__global__ __launch_bounds__(512) void k_gemm1(const float* __restrict__ x,
                                               const ushort* __restrict__ Bt,
                                               ushort* __restrict__ C) {
    __shared__ float  As[128 * 36];    // 18 KB, padded stride 36
    __shared__ ushort Bs[256 * 32];    // 16 KB
    const int tid = threadIdx.x;
    const int lane = tid & 63;
    const int w = tid >> 6;            // 0..7
    const int wm = w >> 2;             // 0..1  (M dir, 64 rows each)
    const int wn = w & 3;              // 0..3  (N dir, 64 cols each)
    const int m0 = blockIdx.x * 128;

    const int fr = lane & 15;
    const int fk = (lane >> 4) * 8;              // k offset (elements)
    const int fksB = fk ^ ((fr & 3) * 8);        // swizzled B read slot

    // A staging: thread -> row = tid>>2 (0..127), colf = (tid&3)*8 floats
    const int arow = tid >> 2;
    const int acol = (tid & 3) * 8;
    const float* xr = x + (size_t)(m0 + arow) * DIN;

    // B staging: round r: global row = r*128 + tid>>2; source col pre-swizzled
    const int brow = tid >> 2;
    const int bcol = ((tid & 3) ^ (brow & 3)) * 8;   // slot c holds chunk c^(row&3)

    f32x4 acc[4][4];
#pragma unroll
    for (int i = 0; i < 4; i++)
#pragma unroll
        for (int j = 0; j < 4; j++) acc[i][j] = (f32x4){0.f, 0.f, 0.f, 0.f};

    // prologue: prefetch A regs for k0 = 0
    float4 a0 = *(const float4*)(xr + min(acol, DIN - 4));
    float4 a1 = *(const float4*)(xr + min(acol + 4, DIN - 4));

    for (int k0 = 0; k0 < KP1; k0 += 32) {
        // write staged A regs (prev-iter compute done at loop-end barrier)
        *(float4*)&As[arow * 36 + acol] = a0;
        *(float4*)&As[arow * 36 + acol + 4] = a1;
        // B: async global->LDS (wave-uniform dest base!)
#pragma unroll
        for (int r = 0; r < 2; r++) {
            const ushort* gb = &Bt[(size_t)(r * 128 + brow) * KP1 + k0 + bcol];
            __builtin_amdgcn_global_load_lds(
                (const __attribute__((address_space(1))) void*)gb,
                (__attribute__((address_space(3))) void*)&Bs[(r * 128 + (tid >> 6) * 16) * 32],
                16, 0, 0);
        }
        // prefetch next-iter A regs (hides HBM latency under MFMA phase)
        {
            const int kn = k0 + 32;
            a0 = *(const float4*)(xr + min(kn + acol, DIN - 4));
            a1 = *(const float4*)(xr + min(kn + acol + 4, DIN - 4));
        }
        __syncthreads();
        bf16x8 af[4], bfv[4];
#pragma unroll
        for (int i = 0; i < 4; i++) {
            const float* ap = &As[(wm * 64 + i * 16 + fr) * 36 + fk];
            f32x4 p = *(const f32x4*)ap;
            f32x4 q = *(const f32x4*)(ap + 4);
            af[i][0] = bcvt(p[0]); af[i][1] = bcvt(p[1]);
            af[i][2] = bcvt(p[2]); af[i][3] = bcvt(p[3]);
            af[i][4] = bcvt(q[0]); af[i][5] = bcvt(q[1]);
            af[i][6] = bcvt(q[2]); af[i][7] = bcvt(q[3]);
            bfv[i] = *(const bf16x8*)&Bs[(wn * 64 + i * 16 + fr) * 32 + fksB];
        }
#pragma unroll
        for (int i = 0; i < 4; i++)
#pragma unroll
            for (int j = 0; j < 4; j++)
                acc[i][j] = __builtin_amdgcn_mfma_f32_16x16x32_bf16(af[i], bfv[j],
                                                                    acc[i][j], 0, 0, 0);
        __syncthreads();
    }

    // epilogue: C/D layout col=lane&15, row=(lane>>4)*4+q
#pragma unroll
    for (int i = 0; i < 4; i++) {
        int row0 = m0 + wm * 64 + i * 16 + (lane >> 4) * 4;
#pragma unroll
        for (int j = 0; j < 4; j++) {
            int col = wn * 64 + j * 16 + fr;
#pragma unroll
            for (int q = 0; q < 4; q++) {
                C[(size_t)(row0 + q) * DH + col] = f2b(acc[i][j][q]);
            }
        }
    }
}

// ---------------------------------------------------------------------------
// bf16 MFMA GEMM (GEMM2): C[M,Ntot] = A[M,KPAD] @ Bt[Ntot,KPAD]^T
// 128x128 tile, BK=32, 4 waves (2x2), 16x16x32 MFMA.
// SYNC STRUCTURE = verified round-0 baseline (two __syncthreads per K-step).
// NEW (validated by R2 cold-pass): As AND Bs XOR(row&3) swizzle (source
// pre-swizzle + matching read offset).  8-way -> 4-way ds_read_b128 conflicts.
// ---------------------------------------------------------------------------
template <int KPAD>
__global__ __launch_bounds__(256) void k_gemm_mfma(const ushort* __restrict__ A,
                                                   const ushort* __restrict__ Bt,
                                                   ushort* __restrict__ C, int Ntot) {
    __shared__ ushort As[128 * 32];
    __shared__ ushort Bs[128 * 32];
    const int tid = threadIdx.x;
    const int lane = tid & 63;
    const int w = tid >> 6;
    const int wm = w >> 1, wn = w & 1;   // 2x2 wave grid, 64x64 per wave
    const int m0 = blockIdx.x * 128;
    const int n0 = blockIdx.y * 128;

    const int srow = tid >> 2;           // 0..63 staging row within 64-group
    const int scol = ((tid & 3) ^ (srow & 3)) * 8;   // pre-swizzled source col

    const int fr = lane & 15;            // fragment row/col
    const int fk = (lane >> 4) * 8;      // fragment k offset (elements)
    const int fks = fk ^ ((fr & 3) * 8); // read slot = chunk ^ (row&3)

    f32x4 acc[4][4];
#pragma unroll
    for (int i = 0; i < 4; i++)
#pragma unroll
        for (int j = 0; j < 4; j++) acc[i][j] = (f32x4){0.f, 0.f, 0.f, 0.f};

    for (int k0 = 0; k0 < KPAD; k0 += 32) {
#pragma unroll
        for (int r = 0; r < 2; r++) {
            const ushort* ga = &A[(size_t)(m0 + r * 64 + srow) * KPAD + k0 + scol];
            __builtin_amdgcn_global_load_lds(
                (const __attribute__((address_space(1))) void*)ga,
                (__attribute__((address_space(3))) void*)&As[(r * 64 + w * 16) * 32],
                16, 0, 0);
            const ushort* gb = &Bt[(size_t)(n0 + r * 64 + srow) * KPAD + k0 + scol];
            __builtin_amdgcn_global_load_lds(
                (const __attribute__((address_space(1))) void*)gb,
                (__attribute__((address_space(3))) void*)&Bs[(r * 64 + w * 16) * 32],
                16, 0, 0);
        }
        __syncthreads();
        bf16x8 af[4], bfv[4];
#pragma unroll
        for (int i = 0; i < 4; i++) {
            af[i]  = *(const bf16x8*)&As[(wm * 64 + i * 16 + fr) * 32 + fks];
            bfv[i] = *(const bf16x8*)&Bs[(wn * 64 + i * 16 + fr) * 32 + fks];
        }
#pragma unroll
        for (int i = 0; i < 4; i++)
#pragma unroll
            for (int j = 0; j < 4; j++)
                acc[i][j] = __builtin_amdgcn_mfma_f32_16x16x32_bf16(af[i], bfv[j],
                                                                    acc[i][j], 0, 0, 0);
        __syncthreads();
    }

    // epilogue: C/D layout col=lane&15, row=(lane>>4)*4+q
#pragma unroll
    for (int i = 0; i < 4; i++) {
        int row0 = m0 + wm * 64 + i * 16 + (lane >> 4) * 4;
#pragma unroll
        for (int j = 0; j < 4; j++) {
            int col = n0 + wn * 64 + j * 16 + fr;
#pragma unroll
            for (int q = 0; q < 4; q++) {
                C[(size_t)(row0 + q) * Ntot + col] = f2b(acc[i][j][q]);
            }
        }
    }
}

// ---------------------------------------------------------------------------
// Fused aggregation + bias (+ReLU) + LayerNorm.  ONE LANE-GROUP PER NODE.
// (unchanged from the passing 227us version)
// ---------------------------------------------------------------------------
template <int D, bool RELU, typename OutT>
__global__ __launch_bounds__(256) void k_agg(const ushort* __restrict__ h,
                                             const int* __restrict__ rowptr,
                                             const int2* __restrict__ edges,
                                             const float* __restrict__ dinv,
                                             const float* __restrict__ bias,
                                             const float* __restrict__ gam,
                                             const float* __restrict__ bet,
                                             OutT* __restrict__ out) {
    constexpr int F = 8;               // features per lane (16B gathers)
    constexpr int GL = D / F;          // lanes per node group (32 / 16)
    constexpr int NPW = 64 / GL;       // nodes per wave (2 / 4)
    __shared__ int2 s_rec[4][64];      // per-wave record slots (2KB)
    const int tid = threadIdx.x;
    const int lane = tid & 63;
    const int wv = tid >> 6;
    const int grp = lane / GL;         // node slot within wave
    const int gl = lane & (GL - 1);    // lane within group
    const int fb = gl * F;             // feature base
    const int g = blockIdx.x & 7;      // graph -> XCD affinity
    const int n = (blockIdx.x >> 3) * (4 * NPW) + wv * NPW + grp;
    const ushort* hg = h + (size_t)g * NN * D;
    const int2* eg = edges + (size_t)g * EE;
    const int r0 = rowptr[g * (NN + 1) + n];
    const int r1 = rowptr[g * (NN + 1) + n + 1];
    const float dn = dinv[g * NN + n];
    int2* srw = &s_rec[wv][grp * GL];  // group's private slot region

    float acc[F];
#pragma unroll
    for (int i = 0; i < F; i++) acc[i] = 0.f;

    for (int base = r0; base < r1; base += GL) {
        const int c = min(GL, r1 - base);
        int2 rec;
        rec.x = 0;
        rec.y = 0;
        if (gl < c) rec = eg[base + gl];
        srw[gl] = rec;
        const int cpad = (c + 3) & ~3;
        for (int j = 0; j < cpad; j += 4) {
            const int4 ra = *(const int4*)&srw[j];      // records j, j+1
            const int4 rb = *(const int4*)&srw[j + 2];  // records j+2, j+3
            u16x8 v0 = *(const u16x8*)&hg[(size_t)ra.x * D + fb];
            u16x8 v1 = *(const u16x8*)&hg[(size_t)ra.z * D + fb];
            u16x8 v2 = *(const u16x8*)&hg[(size_t)rb.x * D + fb];
            u16x8 v3 = *(const u16x8*)&hg[(size_t)rb.z * D + fb];
            const float w0 = __int_as_float(ra.y);
            const float w1 = __int_as_float(ra.w);
            const float w2 = __int_as_float(rb.y);
            const float w3 = __int_as_float(rb.w);
#pragma unroll
            for (int i = 0; i < F; i++) acc[i] = fmaf(bf2f(v0[i]), w0, acc[i]);
#pragma unroll
            for (int i = 0; i < F; i++) acc[i] = fmaf(bf2f(v1[i]), w1, acc[i]);
#pragma unroll
            for (int i = 0; i < F; i++) acc[i] = fmaf(bf2f(v2[i]), w2, acc[i]);
#pragma unroll
            for (int i = 0; i < F; i++) acc[i] = fmaf(bf2f(v3[i]), w3, acc[i]);
        }
    }

    {
        const float ws = dn * dn;
        u16x8 v = *(const u16x8*)&hg[(size_t)n * D + fb];
#pragma unroll
        for (int i = 0; i < F; i++) {
            acc[i] = fmaf(bf2f(v[i]), ws, acc[i]);
            acc[i] += bias[fb + i];
            if (RELU) acc[i] = fmaxf(acc[i], 0.f);
        }
    }
    float s1 = 0.f, s2 = 0.f;
#pragma unroll
    for (int i = 0; i < F; i++) { s1 += acc[i]; s2 += acc[i] * acc[i]; }
#pragma unroll
    for (int o = GL / 2; o > 0; o >>= 1) {
        s1 += __shfl_xor(s1, o);
        s2 += __shfl_xor(s2, o);
    }
    const float mu = s1 / D;
    const float rs = rsqrtf(s2 / D - mu * mu + LN_EPS);

    if constexpr (sizeof(OutT) == 2) {
        u16x8 o;
#pragma unroll
        for (int i = 0; i < F; i++)
            o[i] = f2b((acc[i] - mu) * rs * gam[fb + i] + bet[fb + i]);
        *(u16x8*)&((ushort*)out)[((size_t)g * NN + n) * D + fb] = o;
    } else {
        float* op = &((float*)out)[((size_t)g * NN + n) * D + fb];
        float4 oa, ob;
        oa.x = (acc[0] - mu) * rs * gam[fb + 0] + bet[fb + 0];
        oa.y = (acc[1] - mu) * rs * gam[fb + 1] + bet[fb + 1];
        oa.z = (acc[2] - mu) * rs * gam[fb + 2] + bet[fb + 2];
        oa.w = (acc[3] - mu) * rs * gam[fb + 3] + bet[fb + 3];
        ob.x = (acc[4] - mu) * rs * gam[fb + 4] + bet[fb + 4];
        ob.y = (acc[5] - mu) * rs * gam[fb + 5] + bet[fb + 5];
        ob.z = (acc[6] - mu) * rs * gam[fb + 6] + bet[fb + 6];
        ob.w = (acc[7] - mu) * rs * gam[fb + 7] + bet[fb + 7];
        *(float4*)&op[0] = oa;
        *(float4*)&op[4] = ob;
    }
}

// ---------------------------------------------------------------------------
extern "C" void kernel_launch(void* const* d_in, const int* in_sizes, int n_in,
                              void* d_out, int out_size, void* d_ws, size_t ws_size,
                              hipStream_t stream) {
    const float* x   = (const float*)d_in[0];  // [G,N,300]
    const int*   ei  = (const int*)d_in[1];    // [G,2,E]
    const float* W1  = (const float*)d_in[2];  // [300,256]
    const float* b1  = (const float*)d_in[3];
    const float* g1  = (const float*)d_in[4];
    const float* be1 = (const float*)d_in[5];
    const float* W2  = (const float*)d_in[6];  // [256,128]
    const float* b2  = (const float*)d_in[7];
    const float* g2  = (const float*)d_in[8];
    const float* be2 = (const float*)d_in[9];
    float* out = (float*)d_out;                // [G,N,128]

    // workspace layout (all 16B-aligned)
    char* w = (char*)d_ws;
    ushort* w1t  = (ushort*)w;                        w += (size_t)DH * KP1 * 2;
    ushort* w2t  = (ushort*)w;                        w += (size_t)DOUT * DH * 2;
    ushort* h1b  = (ushort*)w;                        w += (size_t)80000 * DH * 2;    // 41MB
    ushort* out1 = (ushort*)w;                        w += (size_t)80000 * DH * 2;    // 41MB
    int*   cnt    = (int*)w;                          w += (size_t)GG * NN * 4;
    int*   rowptr = (int*)w;                          w += (size_t)GG * (NN + 1) * 4 + 224; // pad to 16B
    int*   slot   = (int*)w;                          w += (size_t)GG * EE * 4;       // 5.1MB
    float* dinv   = (float*)w;                        w += (size_t)GG * NN * 4;
    int2*  edges  = (int2*)w;                         /* G*E*8 = 10.2MB */
    ushort* h2b = h1b;

    // 1. util: zero cnt + cast W1/W2 (one launch)
    k_util<<<dim3((DH * KP1 + 255) / 256), dim3(256), 0, stream>>>(W1, W2, w1t, w2t, cnt);

    // 2. build CSR (atomic slot assign -> scan -> atomic-free fill w/ fat records)
    k_count<<<dim3((EE / 256) * GG), dim3(256), 0, stream>>>(ei, cnt, slot);
    k_scan<<<dim3(GG), dim3(256), 0, stream>>>(cnt, rowptr, dinv);
    k_fill<<<dim3((EE / 256) * GG), dim3(256), 0, stream>>>(ei, rowptr, slot, dinv, edges);

    // 3. h1 = bf16(x) @ W1  (fused cast, 128x256 tile)
    k_gemm1<<<dim3(80000 / 128), dim3(512), 0, stream>>>(x, w1t, h1b);

    // 4. conv1 aggregate + bias + relu + LN -> out1 (bf16): 8 nodes/block
    k_agg<DH, true, ushort><<<dim3((NN / 8) * GG), dim3(256), 0, stream>>>(
        h1b, rowptr, edges, dinv, b1, g1, be1, out1);

    // 5. h2 = out1 @ W2
    k_gemm_mfma<DH><<<dim3(80000 / 128, DOUT / 128), dim3(256), 0, stream>>>(out1, w2t, h2b, DOUT);

    // 6. conv2 aggregate + bias + LN -> d_out (fp32): 16 nodes/block
    k_agg<DOUT, false, float><<<dim3((NN / 16) * GG), dim3(256), 0, stream>>>(
        h2b, rowptr, edges, dinv, b2, g2, be2, out);
}

// Round 4
// 227.511 us; speedup vs baseline: 1.0027x; 1.0027x over previous
//
#include <hip/hip_runtime.h>
#include <hip/hip_bf16.h>

// Problem constants (from reference)
#define GG   8
#define NN   10000
#define EE   160000       // = 625 * 256 exactly
#define DIN  300
#define KP1  320          // DIN padded to mult of 32
#define DH   256
#define DOUT 128
#define LN_EPS 1e-5f

typedef short bf16x8 __attribute__((ext_vector_type(8)));
typedef float f32x4  __attribute__((ext_vector_type(4)));
typedef ushort u16x8 __attribute__((ext_vector_type(8)));

__device__ inline float bf2f(ushort u) {
    union { unsigned int i; float f; } x;
    x.i = ((unsigned int)u) << 16;
    return x.f;
}
__device__ inline ushort f2b(float f) {
    union { float f; unsigned int u; } x;
    x.f = f;
    unsigned int u = x.u;
    return (ushort)((u + 0x7fffu + ((u >> 16) & 1u)) >> 16);  // RNE (finite values)
}
__device__ inline short bcvt(float f) {
    __hip_bfloat16 h = __float2bfloat16(f);   // RNE; compiler emits v_cvt
    return *reinterpret_cast<short*>(&h);
}

// ---------------------------------------------------------------------------
// k_util: zero cnt + cast W1 -> w1t [256][320] + cast W2 -> w2t [128][256]
// ---------------------------------------------------------------------------
__global__ __launch_bounds__(256) void k_util(const float* __restrict__ W1,
                                              const float* __restrict__ W2,
                                              ushort* __restrict__ w1t,
                                              ushort* __restrict__ w2t,
                                              int* __restrict__ cnt) {
    int i = blockIdx.x * blockDim.x + threadIdx.x;
    if (i < GG * NN) cnt[i] = 0;
    if (i < DH * KP1) {
        int n = i / KP1, k = i % KP1;
        w1t[i] = (k < DIN) ? f2b(W1[(size_t)k * DH + n]) : 0;
    }
    if (i < DOUT * DH) {
        int n = i / DH, k = i % DH;
        w2t[i] = f2b(W2[(size_t)k * DOUT + n]);
    }
}

// ---------------------------------------------------------------------------
// CSR build kernels
// ---------------------------------------------------------------------------
__global__ __launch_bounds__(256) void k_count(const int* __restrict__ ei,
                                               int* __restrict__ cnt,
                                               int* __restrict__ slot) {
    int bid = blockIdx.x;
    int g = bid & 7;
    int e = (bid >> 3) * 256 + threadIdx.x;       // e < EE exactly
    int dst = ei[(size_t)g * 2 * EE + EE + e];
    slot[(size_t)g * EE + e] = atomicAdd(&cnt[g * NN + dst], 1);
}

__global__ void k_scan(const int* __restrict__ cnt, int* __restrict__ rowptr,
                       float* __restrict__ dinv) {
    int g = blockIdx.x;
    int t = threadIdx.x;                // 256 threads
    const int per = (NN + 255) / 256;   // 40
    __shared__ int sums[256];
    __shared__ int offs[257];
    int base = t * per;
    int s = 0;
    for (int i = 0; i < per; i++) {
        int n = base + i;
        if (n < NN) s += cnt[g * NN + n];
    }
    sums[t] = s;
    __syncthreads();
    if (t == 0) {
        int acc = 0;
        for (int i = 0; i < 256; i++) { offs[i] = acc; acc += sums[i]; }
        offs[256] = acc;
    }
    __syncthreads();
    int run = offs[t];
    for (int i = 0; i < per; i++) {
        int n = base + i;
        if (n < NN) {
            int c = cnt[g * NN + n];
            rowptr[g * (NN + 1) + n] = run;
            dinv[g * NN + n] = 1.0f / sqrtf(1.0f + (float)c);
            run += c;
        }
    }
    if (t == 255) rowptr[g * (NN + 1) + NN] = offs[256];
}

__global__ __launch_bounds__(256) void k_fill(const int* __restrict__ ei,
                                              const int* __restrict__ rowptr,
                                              const int* __restrict__ slot,
                                              const float* __restrict__ dinv,
                                              int2* __restrict__ edges) {
    int bid = blockIdx.x;
    int g = bid & 7;
    int e = (bid >> 3) * 256 + threadIdx.x;
    int src = ei[(size_t)g * 2 * EE + e];
    int dst = ei[(size_t)g * 2 * EE + EE + e];
    int pos = rowptr[g * (NN + 1) + dst] + slot[(size_t)g * EE + e];
    float coef = dinv[g * NN + src] * dinv[g * NN + dst];
    int2 rec;
    rec.x = src;
    rec.y = __float_as_int(coef);
    edges[(size_t)g * EE + pos] = rec;
}

// ---------------------------------------------------------------------------
// GEMM1 with fused fp32->bf16 cast of A:  C[80000,256] = bf16(x[80000,300]) @ W1
// TILE 64x256, 256 threads (4 waves, 1x4; each wave 64 rows x 64 cols).
// Grid = 1250 blocks (was 625): occupancy was GRID-capped at 2.44 blocks/CU
// with every pipe idle (MfmaUtil 7%, VALU 6.6%, HBM 10%) -> latency-bound.
// More resident blocks = TLP hides the per-iter staging drain (m114/m97).
// SYNC STRUCTURE = verified baseline (two __syncthreads per K-step,
// reg-staged A + ds_write, next-iter A prefetch before barrier).
// Bs XOR(row&3) swizzle kept (validated): source col pre-swizzled, read
// offset matches.  As keeps padded stride 36 floats (2-way, free).
// ---------------------------------------------------------------------------
__global__ __launch_bounds__(256) void k_gemm1(const float* __restrict__ x,
                                               const ushort* __restrict__ Bt,
                                               ushort* __restrict__ C) {
    __shared__ float  As[64 * 36];     // 9 KB, padded stride 36
    __shared__ ushort Bs[256 * 32];    // 16 KB
    const int tid = threadIdx.x;
    const int lane = tid & 63;
    const int w = tid >> 6;            // 0..3
    const int wn = w;                  // N dir, 64 cols each (wm = 0)
    const int m0 = blockIdx.x * 64;

    const int fr = lane & 15;
    const int fk = (lane >> 4) * 8;              // k offset (elements)
    const int fksB = fk ^ ((fr & 3) * 8);        // swizzled B read slot

    // A staging: thread -> row = tid>>2 (0..63), colf = (tid&3)*8 floats
    const int arow = tid >> 2;
    const int acol = (tid & 3) * 8;
    const float* xr = x + (size_t)(m0 + arow) * DIN;

    // B staging: round r: global row = r*64 + tid>>2; source col pre-swizzled
    const int brow4 = (tid >> 2) & 3;                 // row&3 (r*64 == 0 mod 4)
    const int bcol = ((tid & 3) ^ brow4) * 8;         // slot c holds chunk c^(row&3)

    f32x4 acc[4][4];
#pragma unroll
    for (int i = 0; i < 4; i++)
#pragma unroll
        for (int j = 0; j < 4; j++) acc[i][j] = (f32x4){0.f, 0.f, 0.f, 0.f};

    // prologue: prefetch A regs for k0 = 0
    float4 a0 = *(const float4*)(xr + min(acol, DIN - 4));
    float4 a1 = *(const float4*)(xr + min(acol + 4, DIN - 4));

    for (int k0 = 0; k0 < KP1; k0 += 32) {
        // write staged A regs (prev-iter compute done at loop-end barrier)
        *(float4*)&As[arow * 36 + acol] = a0;
        *(float4*)&As[arow * 36 + acol + 4] = a1;
        // B: async global->LDS (wave-uniform dest base!)
#pragma unroll
        for (int r = 0; r < 4; r++) {
            const ushort* gb = &Bt[(size_t)(r * 64 + (tid >> 2)) * KP1 + k0 + bcol];
            __builtin_amdgcn_global_load_lds(
                (const __attribute__((address_space(1))) void*)gb,
                (__attribute__((address_space(3))) void*)&Bs[(r * 64 + w * 16) * 32],
                16, 0, 0);
        }
        // prefetch next-iter A regs (hides HBM latency under MFMA phase)
        {
            const int kn = k0 + 32;
            a0 = *(const float4*)(xr + min(kn + acol, DIN - 4));
            a1 = *(const float4*)(xr + min(kn + acol + 4, DIN - 4));
        }
        __syncthreads();
        bf16x8 af[4], bfv[4];
#pragma unroll
        for (int i = 0; i < 4; i++) {
            const float* ap = &As[(i * 16 + fr) * 36 + fk];
            f32x4 p = *(const f32x4*)ap;
            f32x4 q = *(const f32x4*)(ap + 4);
            af[i][0] = bcvt(p[0]); af[i][1] = bcvt(p[1]);
            af[i][2] = bcvt(p[2]); af[i][3] = bcvt(p[3]);
            af[i][4] = bcvt(q[0]); af[i][5] = bcvt(q[1]);
            af[i][6] = bcvt(q[2]); af[i][7] = bcvt(q[3]);
            bfv[i] = *(const bf16x8*)&Bs[(wn * 64 + i * 16 + fr) * 32 + fksB];
        }
#pragma unroll
        for (int i = 0; i < 4; i++)
#pragma unroll
            for (int j = 0; j < 4; j++)
                acc[i][j] = __builtin_amdgcn_mfma_f32_16x16x32_bf16(af[i], bfv[j],
                                                                    acc[i][j], 0, 0, 0);
        __syncthreads();
    }

    // epilogue: C/D layout col=lane&15, row=(lane>>4)*4+q
#pragma unroll
    for (int i = 0; i < 4; i++) {
        int row0 = m0 + i * 16 + (lane >> 4) * 4;
#pragma unroll
        for (int j = 0; j < 4; j++) {
            int col = wn * 64 + j * 16 + fr;
#pragma unroll
            for (int q = 0; q < 4; q++) {
                C[(size_t)(row0 + q) * DH + col] = f2b(acc[i][j][q]);
            }
        }
    }
}

// ---------------------------------------------------------------------------
// bf16 MFMA GEMM (GEMM2): C[M,Ntot] = A[M,KPAD] @ Bt[Ntot,KPAD]^T
// TILE 64x128, 256 threads, 4 waves (2x2; each wave 32 rows x 64 cols).
// Grid = 1250 blocks (was 625) -> occupancy was grid-capped; see k_gemm1.
// SYNC STRUCTURE = verified baseline (two __syncthreads per K-step).
// As AND Bs XOR(row&3) swizzle kept (validated).
// ---------------------------------------------------------------------------
template <int KPAD>
__global__ __launch_bounds__(256) void k_gemm_mfma(const ushort* __restrict__ A,
                                                   const ushort* __restrict__ Bt,
                                                   ushort* __restrict__ C, int Ntot) {
    __shared__ ushort As[64 * 32];     // 4 KB
    __shared__ ushort Bs[128 * 32];    // 8 KB
    const int tid = threadIdx.x;
    const int lane = tid & 63;
    const int w = tid >> 6;
    const int wm = w >> 1, wn = w & 1;   // 2x2 wave grid, 32x64 per wave
    const int m0 = blockIdx.x * 64;
    const int n0 = blockIdx.y * 128;

    const int srow = tid >> 2;                       // 0..63 staging row
    const int scol = ((tid & 3) ^ (srow & 3)) * 8;   // pre-swizzled source col

    const int fr = lane & 15;            // fragment row/col
    const int fk = (lane >> 4) * 8;      // fragment k offset (elements)
    const int fks = fk ^ ((fr & 3) * 8); // read slot = chunk ^ (row&3)

    f32x4 acc[2][4];
#pragma unroll
    for (int i = 0; i < 2; i++)
#pragma unroll
        for (int j = 0; j < 4; j++) acc[i][j] = (f32x4){0.f, 0.f, 0.f, 0.f};

    for (int k0 = 0; k0 < KPAD; k0 += 32) {
        // A: 64 rows via one gload_lds per wave (wave w covers rows w*16..w*16+15)
        {
            const ushort* ga = &A[(size_t)(m0 + srow) * KPAD + k0 + scol];
            __builtin_amdgcn_global_load_lds(
                (const __attribute__((address_space(1))) void*)ga,
                (__attribute__((address_space(3))) void*)&As[(w * 16) * 32],
                16, 0, 0);
        }
        // B: 128 rows via two rounds
#pragma unroll
        for (int r = 0; r < 2; r++) {
            const ushort* gb = &Bt[(size_t)(n0 + r * 64 + srow) * KPAD + k0 + scol];
            __builtin_amdgcn_global_load_lds(
                (const __attribute__((address_space(1))) void*)gb,
                (__attribute__((address_space(3))) void*)&Bs[(r * 64 + w * 16) * 32],
                16, 0, 0);
        }
        __syncthreads();
        bf16x8 af[2], bfv[4];
#pragma unroll
        for (int i = 0; i < 2; i++)
            af[i]  = *(const bf16x8*)&As[(wm * 32 + i * 16 + fr) * 32 + fks];
#pragma unroll
        for (int j = 0; j < 4; j++)
            bfv[j] = *(const bf16x8*)&Bs[(wn * 64 + j * 16 + fr) * 32 + fks];
#pragma unroll
        for (int i = 0; i < 2; i++)
#pragma unroll
            for (int j = 0; j < 4; j++)
                acc[i][j] = __builtin_amdgcn_mfma_f32_16x16x32_bf16(af[i], bfv[j],
                                                                    acc[i][j], 0, 0, 0);
        __syncthreads();
    }

    // epilogue: C/D layout col=lane&15, row=(lane>>4)*4+q
#pragma unroll
    for (int i = 0; i < 2; i++) {
        int row0 = m0 + wm * 32 + i * 16 + (lane >> 4) * 4;
#pragma unroll
        for (int j = 0; j < 4; j++) {
            int col = n0 + wn * 64 + j * 16 + fr;
#pragma unroll
            for (int q = 0; q < 4; q++) {
                C[(size_t)(row0 + q) * Ntot + col] = f2b(acc[i][j][q]);
            }
        }
    }
}

// ---------------------------------------------------------------------------
// Fused aggregation + bias (+ReLU) + LayerNorm.  ONE LANE-GROUP PER NODE.
// (unchanged from the passing 227us version)
// ---------------------------------------------------------------------------
template <int D, bool RELU, typename OutT>
__global__ __launch_bounds__(256) void k_agg(const ushort* __restrict__ h,
                                             const int* __restrict__ rowptr,
                                             const int2* __restrict__ edges,
                                             const float* __restrict__ dinv,
                                             const float* __restrict__ bias,
                                             const float* __restrict__ gam,
                                             const float* __restrict__ bet,
                                             OutT* __restrict__ out) {
    constexpr int F = 8;               // features per lane (16B gathers)
    constexpr int GL = D / F;          // lanes per node group (32 / 16)
    constexpr int NPW = 64 / GL;       // nodes per wave (2 / 4)
    __shared__ int2 s_rec[4][64];      // per-wave record slots (2KB)
    const int tid = threadIdx.x;
    const int lane = tid & 63;
    const int wv = tid >> 6;
    const int grp = lane / GL;         // node slot within wave
    const int gl = lane & (GL - 1);    // lane within group
    const int fb = gl * F;             // feature base
    const int g = blockIdx.x & 7;      // graph -> XCD affinity
    const int n = (blockIdx.x >> 3) * (4 * NPW) + wv * NPW + grp;
    const ushort* hg = h + (size_t)g * NN * D;
    const int2* eg = edges + (size_t)g * EE;
    const int r0 = rowptr[g * (NN + 1) + n];
    const int r1 = rowptr[g * (NN + 1) + n + 1];
    const float dn = dinv[g * NN + n];
    int2* srw = &s_rec[wv][grp * GL];  // group's private slot region

    float acc[F];
#pragma unroll
    for (int i = 0; i < F; i++) acc[i] = 0.f;

    for (int base = r0; base < r1; base += GL) {
        const int c = min(GL, r1 - base);
        int2 rec;
        rec.x = 0;
        rec.y = 0;
        if (gl < c) rec = eg[base + gl];
        srw[gl] = rec;
        const int cpad = (c + 3) & ~3;
        for (int j = 0; j < cpad; j += 4) {
            const int4 ra = *(const int4*)&srw[j];      // records j, j+1
            const int4 rb = *(const int4*)&srw[j + 2];  // records j+2, j+3
            u16x8 v0 = *(const u16x8*)&hg[(size_t)ra.x * D + fb];
            u16x8 v1 = *(const u16x8*)&hg[(size_t)ra.z * D + fb];
            u16x8 v2 = *(const u16x8*)&hg[(size_t)rb.x * D + fb];
            u16x8 v3 = *(const u16x8*)&hg[(size_t)rb.z * D + fb];
            const float w0 = __int_as_float(ra.y);
            const float w1 = __int_as_float(ra.w);
            const float w2 = __int_as_float(rb.y);
            const float w3 = __int_as_float(rb.w);
#pragma unroll
            for (int i = 0; i < F; i++) acc[i] = fmaf(bf2f(v0[i]), w0, acc[i]);
#pragma unroll
            for (int i = 0; i < F; i++) acc[i] = fmaf(bf2f(v1[i]), w1, acc[i]);
#pragma unroll
            for (int i = 0; i < F; i++) acc[i] = fmaf(bf2f(v2[i]), w2, acc[i]);
#pragma unroll
            for (int i = 0; i < F; i++) acc[i] = fmaf(bf2f(v3[i]), w3, acc[i]);
        }
    }

    {
        const float ws = dn * dn;
        u16x8 v = *(const u16x8*)&hg[(size_t)n * D + fb];
#pragma unroll
        for (int i = 0; i < F; i++) {
            acc[i] = fmaf(bf2f(v[i]), ws, acc[i]);
            acc[i] += bias[fb + i];
            if (RELU) acc[i] = fmaxf(acc[i], 0.f);
        }
    }
    float s1 = 0.f, s2 = 0.f;
#pragma unroll
    for (int i = 0; i < F; i++) { s1 += acc[i]; s2 += acc[i] * acc[i]; }
#pragma unroll
    for (int o = GL / 2; o > 0; o >>= 1) {
        s1 += __shfl_xor(s1, o);
        s2 += __shfl_xor(s2, o);
    }
    const float mu = s1 / D;
    const float rs = rsqrtf(s2 / D - mu * mu + LN_EPS);

    if constexpr (sizeof(OutT) == 2) {
        u16x8 o;
#pragma unroll
        for (int i = 0; i < F; i++)
            o[i] = f2b((acc[i] - mu) * rs * gam[fb + i] + bet[fb + i]);
        *(u16x8*)&((ushort*)out)[((size_t)g * NN + n) * D + fb] = o;
    } else {
        float* op = &((float*)out)[((size_t)g * NN + n) * D + fb];
        float4 oa, ob;
        oa.x = (acc[0] - mu) * rs * gam[fb + 0] + bet[fb + 0];
        oa.y = (acc[1] - mu) * rs * gam[fb + 1] + bet[fb + 1];
        oa.z = (acc[2] - mu) * rs * gam[fb + 2] + bet[fb + 2];
        oa.w = (acc[3] - mu) * rs * gam[fb + 3] + bet[fb + 3];
        ob.x = (acc[4] - mu) * rs * gam[fb + 4] + bet[fb + 4];
        ob.y = (acc[5] - mu) * rs * gam[fb + 5] + bet[fb + 5];
        ob.z = (acc[6] - mu) * rs * gam[fb + 6] + bet[fb + 6];
        ob.w = (acc[7] - mu) * rs * gam[fb + 7] + bet[fb + 7];
        *(float4*)&op[0] = oa;
        *(float4*)&op[4] = ob;
    }
}

// ---------------------------------------------------------------------------
extern "C" void kernel_launch(void* const* d_in, const int* in_sizes, int n_in,
                              void* d_out, int out_size, void* d_ws, size_t ws_size,
                              hipStream_t stream) {
    const float* x   = (const float*)d_in[0];  // [G,N,300]
    const int*   ei  = (const int*)d_in[1];    // [G,2,E]
    const float* W1  = (const float*)d_in[2];  // [300,256]
    const float* b1  = (const float*)d_in[3];
    const float* g1  = (const float*)d_in[4];
    const float* be1 = (const float*)d_in[5];
    const float* W2  = (const float*)d_in[6];  // [256,128]
    const float* b2  = (const float*)d_in[7];
    const float* g2  = (const float*)d_in[8];
    const float* be2 = (const float*)d_in[9];
    float* out = (float*)d_out;                // [G,N,128]

    // workspace layout (all 16B-aligned)
    char* w = (char*)d_ws;
    ushort* w1t  = (ushort*)w;                        w += (size_t)DH * KP1 * 2;
    ushort* w2t  = (ushort*)w;                        w += (size_t)DOUT * DH * 2;
    ushort* h1b  = (ushort*)w;                        w += (size_t)80000 * DH * 2;    // 41MB
    ushort* out1 = (ushort*)w;                        w += (size_t)80000 * DH * 2;    // 41MB
    int*   cnt    = (int*)w;                          w += (size_t)GG * NN * 4;
    int*   rowptr = (int*)w;                          w += (size_t)GG * (NN + 1) * 4 + 224; // pad to 16B
    int*   slot   = (int*)w;                          w += (size_t)GG * EE * 4;       // 5.1MB
    float* dinv   = (float*)w;                        w += (size_t)GG * NN * 4;
    int2*  edges  = (int2*)w;                         /* G*E*8 = 10.2MB */
    ushort* h2b = h1b;

    // 1. util: zero cnt + cast W1/W2 (one launch)
    k_util<<<dim3((DH * KP1 + 255) / 256), dim3(256), 0, stream>>>(W1, W2, w1t, w2t, cnt);

    // 2. build CSR (atomic slot assign -> scan -> atomic-free fill w/ fat records)
    k_count<<<dim3((EE / 256) * GG), dim3(256), 0, stream>>>(ei, cnt, slot);
    k_scan<<<dim3(GG), dim3(256), 0, stream>>>(cnt, rowptr, dinv);
    k_fill<<<dim3((EE / 256) * GG), dim3(256), 0, stream>>>(ei, rowptr, slot, dinv, edges);

    // 3. h1 = bf16(x) @ W1  (fused cast, 64x256 tile, grid 1250)
    k_gemm1<<<dim3(80000 / 64), dim3(256), 0, stream>>>(x, w1t, h1b);

    // 4. conv1 aggregate + bias + relu + LN -> out1 (bf16): 8 nodes/block
    k_agg<DH, true, ushort><<<dim3((NN / 8) * GG), dim3(256), 0, stream>>>(
        h1b, rowptr, edges, dinv, b1, g1, be1, out1);

    // 5. h2 = out1 @ W2  (64x128 tile, grid 1250)
    k_gemm_mfma<DH><<<dim3(80000 / 64, DOUT / 128), dim3(256), 0, stream>>>(out1, w2t, h2b, DOUT);

    // 6. conv2 aggregate + bias + LN -> d_out (fp32): 16 nodes/block
    k_agg<DOUT, false, float><<<dim3((NN / 16) * GG), dim3(256), 0, stream>>>(
        h2b, rowptr, edges, dinv, b2, g2, be2, out);
}